// Round 1
// baseline (1266.448 us; speedup 1.0000x reference)
//
#include <hip/hip_runtime.h>

#define D 128
#define ROWS 64   // rows of agg per GEMM block

// ---------------------------------------------------------------------------
// Phase 1: agg[dst,:] += e * feat[src,:] ; esum[dst] += e ; deg[dst] += 1
// 32 threads per edge, float4 gather, per-element fp32 atomics.
// ---------------------------------------------------------------------------
__global__ __launch_bounds__(256) void scatter_k(
    const float* __restrict__ feat,
    const int* __restrict__ esrc,
    const int* __restrict__ edst,
    const float* __restrict__ ee,
    float* __restrict__ agg,    // [N*D] (aliases d_out)
    float* __restrict__ esum,   // [N]
    float* __restrict__ degf,   // [N]
    int E)
{
    int t = blockIdx.x * 256 + threadIdx.x;
    int edge = t >> 5;
    if (edge >= E) return;
    int lane = t & 31;
    int s = esrc[edge];
    int d = edst[edge];
    float ev = ee[edge];
    float4 v = ((const float4*)(feat + (size_t)s * D))[lane];
    float* ag = agg + (size_t)d * D + lane * 4;
    atomicAdd(ag + 0, ev * v.x);
    atomicAdd(ag + 1, ev * v.y);
    atomicAdd(ag + 2, ev * v.z);
    atomicAdd(ag + 3, ev * v.w);
    if (lane == 0) {
        atomicAdd(esum + d, ev);
        atomicAdd(degf + d, 1.0f);
    }
}

// ---------------------------------------------------------------------------
// Phase 2: out[n,:] = relu((agg[n,:]@W^T + esum[n]*b)/max(deg,1)) + alpha[n]*feat[n,:]
// K-tiled (KT=32) LDS GEMM. Block = 256 threads computes 64 rows x 128 cols.
// Thread tile: 8 rows x 4 cols (cols j32, j32+32, j32+64, j32+96).
// agg aliases out: each block reads only its own rows before writing them.
// ---------------------------------------------------------------------------
__global__ __launch_bounds__(256) void gemm_k(
    const float* __restrict__ agg,   // == out
    const float* __restrict__ feat,
    const float* __restrict__ alpha, // [N]
    const float* __restrict__ W,     // [D*D] row-major W[j][k]
    const float* __restrict__ b,     // [D]
    const float* __restrict__ esum,
    const float* __restrict__ degf,
    float* __restrict__ out,
    int N)
{
    __shared__ float Wl[D * 36];     // W[j][k-local], stride 36 (pad), 18.4 KB
    __shared__ float At[ROWS * 32];  // A[r][k-local], 8 KB

    const int tid = threadIdx.x;
    const int base = blockIdx.x * ROWS;
    const int j32 = tid & 31;        // column group
    const int rg = tid >> 5;         // row group 0..7

    float acc[8][4];
#pragma unroll
    for (int i = 0; i < 8; ++i)
#pragma unroll
        for (int m = 0; m < 4; ++m) acc[i][m] = 0.0f;

    for (int kt = 0; kt < 4; ++kt) {          // K tiles of 32
        // stage W chunk: rows j=0..127, k = kt*32 .. kt*32+31
#pragma unroll
        for (int q = 0; q < 4; ++q) {         // 1024 float4 / 256 threads
            int idx = q * 256 + tid;
            int j = idx >> 3;
            int c4 = idx & 7;
            float4 v = *(const float4*)&W[(size_t)j * D + kt * 32 + c4 * 4];
            *(float4*)&Wl[j * 36 + c4 * 4] = v;
        }
        // stage A chunk: rows base..base+63, same k range
#pragma unroll
        for (int q = 0; q < 2; ++q) {         // 512 float4 / 256 threads
            int idx = q * 256 + tid;
            int r = idx >> 3;
            int c4 = idx & 7;
            int n = base + r;
            float4 v = make_float4(0.f, 0.f, 0.f, 0.f);
            if (n < N)
                v = *(const float4*)&agg[(size_t)n * D + kt * 32 + c4 * 4];
            *(float4*)&At[r * 32 + c4 * 4] = v;
        }
        __syncthreads();

#pragma unroll
        for (int k0 = 0; k0 < 32; k0 += 4) {
            float4 wv[4];
#pragma unroll
            for (int m = 0; m < 4; ++m)
                wv[m] = *(const float4*)&Wl[(j32 + 32 * m) * 36 + k0];
#pragma unroll
            for (int i = 0; i < 8; ++i) {
                int r = rg * 8 + i;
                float4 av = *(const float4*)&At[r * 32 + k0];
#pragma unroll
                for (int m = 0; m < 4; ++m) {
                    acc[i][m] += av.x * wv[m].x;
                    acc[i][m] += av.y * wv[m].y;
                    acc[i][m] += av.z * wv[m].z;
                    acc[i][m] += av.w * wv[m].w;
                }
            }
        }
        __syncthreads();
    }

    // fused epilogue
#pragma unroll
    for (int i = 0; i < 8; ++i) {
        int r = rg * 8 + i;
        int n = base + r;
        if (n >= N) continue;
        float es = esum[n];
        float inv = 1.0f / fmaxf(degf[n], 1.0f);
        float al = alpha[n];
#pragma unroll
        for (int m = 0; m < 4; ++m) {
            int c = j32 + 32 * m;
            float v = (acc[i][m] + es * b[c]) * inv;
            v = fmaxf(v, 0.0f);
            out[(size_t)n * D + c] = v + al * feat[(size_t)n * D + c];
        }
    }
}

extern "C" void kernel_launch(void* const* d_in, const int* in_sizes, int n_in,
                              void* d_out, int out_size, void* d_ws, size_t ws_size,
                              hipStream_t stream) {
    const float* feat  = (const float*)d_in[0];
    const float* alpha = (const float*)d_in[1];
    const int*   esrc  = (const int*)d_in[2];
    const int*   edst  = (const int*)d_in[3];
    const float* ee    = (const float*)d_in[4];
    const float* W     = (const float*)d_in[5];
    const float* b     = (const float*)d_in[6];
    float* out = (float*)d_out;

    const int E = in_sizes[2];
    const int N = in_sizes[0] / D;

    float* esum = (float*)d_ws;
    float* degf = esum + N;

    // zero accumulators (d_out doubles as agg buffer)
    hipMemsetAsync(d_out, 0, (size_t)N * D * sizeof(float), stream);
    hipMemsetAsync(d_ws, 0, (size_t)2 * N * sizeof(float), stream);

    long long sthreads = (long long)E * 32;
    int sblocks = (int)((sthreads + 255) / 256);
    scatter_k<<<sblocks, 256, 0, stream>>>(feat, esrc, edst, ee, out, esum, degf, E);

    int gblocks = (N + ROWS - 1) / ROWS;
    gemm_k<<<gblocks, 256, 0, stream>>>(out, feat, alpha, W, b, esum, degf, out, N);
}

// Round 2
// 250.422 us; speedup vs baseline: 5.0573x; 5.0573x over previous
//
#include <hip/hip_runtime.h>

#define D 128
#define ROWS 64   // rows per GEMM block

// ---------------------------------------------------------------------------
// CSR build phase 1: histogram of dst
// ---------------------------------------------------------------------------
__global__ __launch_bounds__(256) void hist_k(
    const int* __restrict__ edst, int* __restrict__ cnt, int E)
{
    int i = blockIdx.x * 256 + threadIdx.x;
    if (i < E) atomicAdd(&cnt[edst[i]], 1);
}

// ---------------------------------------------------------------------------
// CSR build phase 2: bucket base allocation.
// Wave-level exclusive scan of cnt + one global ticket atomic per wave.
// Bucket order is arrival-order (non-deterministic) but buckets are disjoint
// and cover [0,E) — only fp32 summation order within a row varies (<< thresh).
// Also writes degf = (float)cnt.
// ---------------------------------------------------------------------------
__global__ __launch_bounds__(256) void alloc_k(
    const int* __restrict__ cnt, int* __restrict__ ticket,
    int* __restrict__ rbase, int* __restrict__ fbase,
    float* __restrict__ degf, int N)
{
    int n = blockIdx.x * 256 + threadIdx.x;
    int lane = threadIdx.x & 63;
    int c = (n < N) ? cnt[n] : 0;

    // inclusive scan over the 64-lane wave
    int inc = c;
#pragma unroll
    for (int off = 1; off < 64; off <<= 1) {
        int up = __shfl_up(inc, off, 64);
        if (lane >= off) inc += up;
    }
    int wave_total = __shfl(inc, 63, 64);
    int wave_base = 0;
    if (lane == 63) wave_base = atomicAdd(ticket, wave_total);
    wave_base = __shfl(wave_base, 63, 64);
    int base = wave_base + inc - c;   // exclusive prefix

    if (n < N) {
        rbase[n] = base;
        fbase[n] = base;
        degf[n] = (float)c;
    }
}

// ---------------------------------------------------------------------------
// CSR build phase 3: scatter edges into buckets, packed (src, e_bits).
// ---------------------------------------------------------------------------
__global__ __launch_bounds__(256) void fill_k(
    const int* __restrict__ esrc, const int* __restrict__ edst,
    const float* __restrict__ ee, int* __restrict__ fbase,
    int2* __restrict__ perm, int E)
{
    int i = blockIdx.x * 256 + threadIdx.x;
    if (i >= E) return;
    int d = edst[i];
    int slot = atomicAdd(&fbase[d], 1);
    perm[slot] = make_int2(esrc[i], __float_as_int(ee[i]));
}

// ---------------------------------------------------------------------------
// Pull-mode aggregation: one wave per node, no atomics.
// agg[n,:] = sum_{edges->n} e * feat[src,:]   (float2 per lane)
// ---------------------------------------------------------------------------
__global__ __launch_bounds__(256) void agg_k(
    const float* __restrict__ feat,
    const int2* __restrict__ perm,
    const int* __restrict__ rbase,
    const int* __restrict__ cnt,
    float* __restrict__ agg,    // d_out
    float* __restrict__ esum,
    int N)
{
    int node = blockIdx.x * 4 + (threadIdx.x >> 6);
    if (node >= N) return;
    int lane = threadIdx.x & 63;
    int base = rbase[node];
    int c = cnt[node];

    float2 acc = make_float2(0.f, 0.f);
    float es = 0.f;

    int j = 0;
    for (; j + 4 <= c; j += 4) {
        int2 p0 = perm[base + j + 0];
        int2 p1 = perm[base + j + 1];
        int2 p2 = perm[base + j + 2];
        int2 p3 = perm[base + j + 3];
        float2 v0 = ((const float2*)(feat + (size_t)p0.x * D))[lane];
        float2 v1 = ((const float2*)(feat + (size_t)p1.x * D))[lane];
        float2 v2 = ((const float2*)(feat + (size_t)p2.x * D))[lane];
        float2 v3 = ((const float2*)(feat + (size_t)p3.x * D))[lane];
        float e0 = __int_as_float(p0.y), e1 = __int_as_float(p1.y);
        float e2 = __int_as_float(p2.y), e3 = __int_as_float(p3.y);
        acc.x += e0 * v0.x; acc.y += e0 * v0.y;
        acc.x += e1 * v1.x; acc.y += e1 * v1.y;
        acc.x += e2 * v2.x; acc.y += e2 * v2.y;
        acc.x += e3 * v3.x; acc.y += e3 * v3.y;
        es += e0 + e1 + e2 + e3;
    }
    for (; j < c; ++j) {
        int2 p = perm[base + j];
        float e = __int_as_float(p.y);
        float2 v = ((const float2*)(feat + (size_t)p.x * D))[lane];
        acc.x += e * v.x; acc.y += e * v.y;
        es += e;
    }

    ((float2*)(agg + (size_t)node * D))[lane] = acc;
    if (lane == 0) esum[node] = es;
}

// ---------------------------------------------------------------------------
// Phase 2 GEMM (unchanged): out = relu((agg@W^T + esum*b)/max(deg,1)) + alpha*feat
// ---------------------------------------------------------------------------
__global__ __launch_bounds__(256) void gemm_k(
    const float* __restrict__ agg,   // == out
    const float* __restrict__ feat,
    const float* __restrict__ alpha, // [N]
    const float* __restrict__ W,     // [D*D] row-major W[j][k]
    const float* __restrict__ b,     // [D]
    const float* __restrict__ esum,
    const float* __restrict__ degf,
    float* __restrict__ out,
    int N)
{
    __shared__ float Wl[D * 36];
    __shared__ float At[ROWS * 32];

    const int tid = threadIdx.x;
    const int base = blockIdx.x * ROWS;
    const int j32 = tid & 31;
    const int rg = tid >> 5;

    float acc[8][4];
#pragma unroll
    for (int i = 0; i < 8; ++i)
#pragma unroll
        for (int m = 0; m < 4; ++m) acc[i][m] = 0.0f;

    for (int kt = 0; kt < 4; ++kt) {
#pragma unroll
        for (int q = 0; q < 4; ++q) {
            int idx = q * 256 + tid;
            int jj = idx >> 3;
            int c4 = idx & 7;
            float4 v = *(const float4*)&W[(size_t)jj * D + kt * 32 + c4 * 4];
            *(float4*)&Wl[jj * 36 + c4 * 4] = v;
        }
#pragma unroll
        for (int q = 0; q < 2; ++q) {
            int idx = q * 256 + tid;
            int r = idx >> 3;
            int c4 = idx & 7;
            int n = base + r;
            float4 v = make_float4(0.f, 0.f, 0.f, 0.f);
            if (n < N)
                v = *(const float4*)&agg[(size_t)n * D + kt * 32 + c4 * 4];
            *(float4*)&At[r * 32 + c4 * 4] = v;
        }
        __syncthreads();

#pragma unroll
        for (int k0 = 0; k0 < 32; k0 += 4) {
            float4 wv[4];
#pragma unroll
            for (int m = 0; m < 4; ++m)
                wv[m] = *(const float4*)&Wl[(j32 + 32 * m) * 36 + k0];
#pragma unroll
            for (int i = 0; i < 8; ++i) {
                int r = rg * 8 + i;
                float4 av = *(const float4*)&At[r * 32 + k0];
#pragma unroll
                for (int m = 0; m < 4; ++m) {
                    acc[i][m] += av.x * wv[m].x;
                    acc[i][m] += av.y * wv[m].y;
                    acc[i][m] += av.z * wv[m].z;
                    acc[i][m] += av.w * wv[m].w;
                }
            }
        }
        __syncthreads();
    }

#pragma unroll
    for (int i = 0; i < 8; ++i) {
        int r = rg * 8 + i;
        int n = base + r;
        if (n >= N) continue;
        float es = esum[n];
        float inv = 1.0f / fmaxf(degf[n], 1.0f);
        float al = alpha[n];
#pragma unroll
        for (int m = 0; m < 4; ++m) {
            int c = j32 + 32 * m;
            float v = (acc[i][m] + es * b[c]) * inv;
            v = fmaxf(v, 0.0f);
            out[(size_t)n * D + c] = v + al * feat[(size_t)n * D + c];
        }
    }
}

extern "C" void kernel_launch(void* const* d_in, const int* in_sizes, int n_in,
                              void* d_out, int out_size, void* d_ws, size_t ws_size,
                              hipStream_t stream) {
    const float* feat  = (const float*)d_in[0];
    const float* alpha = (const float*)d_in[1];
    const int*   esrc  = (const int*)d_in[2];
    const int*   edst  = (const int*)d_in[3];
    const float* ee    = (const float*)d_in[4];
    const float* W     = (const float*)d_in[5];
    const float* b     = (const float*)d_in[6];
    float* out = (float*)d_out;

    const int E = in_sizes[2];
    const int N = in_sizes[0] / D;

    // workspace layout
    int2*  perm   = (int2*)d_ws;              // E entries (8B each)
    int*   cnt    = (int*)(perm + E);         // N
    int*   ticket = cnt + N;                  // 1
    int*   rbase  = ticket + 1;               // N
    int*   fbase  = rbase + N;                // N
    float* esum   = (float*)(fbase + N);      // N
    float* degf   = esum + N;                 // N

    // zero cnt + ticket (contiguous)
    hipMemsetAsync(cnt, 0, (size_t)(N + 1) * sizeof(int), stream);

    int eblocks = (E + 255) / 256;
    int nblocks = (N + 255) / 256;

    hist_k<<<eblocks, 256, 0, stream>>>(edst, cnt, E);
    alloc_k<<<nblocks, 256, 0, stream>>>(cnt, ticket, rbase, fbase, degf, N);
    fill_k<<<eblocks, 256, 0, stream>>>(esrc, edst, ee, fbase, perm, E);

    int ablocks = (N + 3) / 4;
    agg_k<<<ablocks, 256, 0, stream>>>(feat, perm, rbase, cnt, out, esum, N);

    int gblocks = (N + ROWS - 1) / ROWS;
    gemm_k<<<gblocks, 256, 0, stream>>>(out, feat, alpha, W, b, esum, degf, out, N);
}